// Round 10
// baseline (235.872 us; speedup 1.0000x reference)
//
#include <hip/hip_runtime.h>
#include <cstdint>
#include <cstddef>

// ws layout (float offsets)
#define WS_WBIG 0            // 3072*32 = 98304
#define WS_BMAT 98304        // bmatT: 24*640 = 15360
#define WS_BBIG 113664       // 24 (+pad to 64)
#define WS_ND   113728       // 4*8192*23 = 753664
#define WS_ED   867392       // 4*28672*23 = 2637824
#define WS_DEAD 3505216      // diagnostic sink (576 floats)

// output offsets (floats)
#define OUT_IND 0
#define OUT_LAB 28672
#define OUT_LRP 57344
#define OUT_CRP 98304
#define OUT_MRP 122880
#define OUT_LRN 237568
#define OUT_CRN 339968
#define OUT_MRN 401408

__device__ __constant__ int d_pi[28] = {0,0,0,0,0,0,0,1,1,1,1,1,1,2,2,2,2,2,3,3,3,3,4,4,4,5,5,6};
__device__ __constant__ int d_pj[28] = {1,2,3,4,5,6,7,2,3,4,5,6,7,3,4,5,6,7,4,5,6,7,5,6,7,6,7,7};

__device__ __forceinline__ float wh_at(const float* wlr, const float* wcr, const float* wmr,
                                       int j, int h) {
  return (h < 5) ? wlr[j*5 + h] : (h < 8) ? wcr[j*3 + (h-5)] : wmr[j*14 + (h-8)];
}

// global -> LDS direct (16B per lane); LDS dest = wave-uniform base + lane*16
__device__ __forceinline__ void load_lds16(const float* g, float* l) {
  __builtin_amdgcn_global_load_lds((const __attribute__((address_space(1))) void*)g,
                                   (__attribute__((address_space(3))) void*)l, 16, 0, 0);
}

// ---------------- prep1: bmatT[24][640] and b_big ----------------
__global__ __launch_bounds__(256) void prep1(
    const float* __restrict__ w_rel, const float* __restrict__ w_ind2,
    const float* __restrict__ w_lr, const float* __restrict__ w_cr, const float* __restrict__ w_mr,
    const float* __restrict__ b_ind1, const float* __restrict__ b_ind2,
    const float* __restrict__ b_rel,
    const float* __restrict__ b_lr, const float* __restrict__ b_cr, const float* __restrict__ b_mr,
    float* __restrict__ bmat, float* __restrict__ bbig) {
  int bid = blockIdx.x, tid = threadIdx.x;
  if (bid < 128) {                         // T1 col m: bmatT[1+h][m] = sum_j Wrel2[m][j]*Wh[j][h]
    int m = bid;
    __shared__ float swr[512];
    const float* wr2 = w_rel + (size_t)(3072 + m)*512;
    swr[tid]       = wr2[tid];
    swr[tid + 256] = wr2[tid + 256];
    __syncthreads();
    int h = tid >> 3, q = tid & 7;
    if (h < 22) {
      float a = 0.f;
#pragma unroll 8
      for (int jj = 0; jj < 64; ++jj) {
        int j = jj*8 + q;
        a = fmaf(swr[j], wh_at(w_lr, w_cr, w_mr, j, h), a);
      }
      a += __shfl_xor(a, 1); a += __shfl_xor(a, 2); a += __shfl_xor(a, 4);
      if (q == 0) bmat[(1 + h)*640 + m] = a;
    }
    if (tid == 248) bmat[0*640 + m]  = w_ind2[m];
    if (tid == 249) bmat[23*640 + m] = 0.f;
  } else if (bid == 128) {                 // biases
    __shared__ float sbrel[512];
    for (int j = tid; j < 512; j += 256) {
      float a = b_rel[j];
#pragma unroll 4
      for (int m = 0; m < 128; ++m)
        a = fmaf(b_ind1[m], w_rel[(size_t)(3072 + m)*512 + j], a);
      sbrel[j] = a;
    }
    __syncthreads();
    int h = tid >> 3, q = tid & 7;
    if (h < 22) {
      float bh = (h < 5) ? b_lr[h] : (h < 8) ? b_cr[h-5] : b_mr[h-8];
      float a = 0.f;
#pragma unroll 8
      for (int jj = 0; jj < 64; ++jj) {
        int j = jj*8 + q;
        a = fmaf(sbrel[j], wh_at(w_lr, w_cr, w_mr, j, h), a);
      }
      a += __shfl_xor(a, 1); a += __shfl_xor(a, 2); a += __shfl_xor(a, 4);
      if (q == 0) bbig[1 + h] = a + bh;
    } else if (tid >= 248) {
      int q2 = tid & 7;
      float a = 0.f;
#pragma unroll
      for (int t = 0; t < 16; ++t)
        a = fmaf(b_ind1[q2*16 + t], w_ind2[q2*16 + t], a);
      a += __shfl_xor(a, 1); a += __shfl_xor(a, 2); a += __shfl_xor(a, 4);
      if (tid == 248) bbig[0]  = a + b_ind2[0];
      if (tid == 250) bbig[23] = 0.f;
    }
  } else {                                 // WhE: bmatT[n][128+j], bids 129..176
    int idx = (bid - 129)*256 + tid;
    int j = idx / 24, n = idx % 24;
    float v = (n >= 1 && n <= 22) ? wh_at(w_lr, w_cr, w_mr, j, n - 1) : 0.f;
    bmat[n*640 + 128 + j] = v;
  }
}

// ---------------- prep2: W_big[k][n] (pitch 32) = [W_ind1|W_rel][k] . bmatT[n][:]
__global__ __launch_bounds__(256) void prep2(
    const float* __restrict__ w_ind1, const float* __restrict__ w_rel,
    const float* __restrict__ bmat, float* __restrict__ wbig) {
  int g = blockIdx.x*256 + threadIdx.x;    // 294912 = 73728 outputs x 4 quarters
  int gid = g >> 2, q = g & 3;
  int k = gid / 24, n = gid % 24;
  float a = 0.f;
  if (n != 23) {
    const float* wr = w_rel + (size_t)k*512;
    const float* bn = bmat + n*640;
    if (q == 0) {
      const float* w1 = w_ind1 + (size_t)k*128;
#pragma unroll 8
      for (int i = 0; i < 128; ++i) a = fmaf(w1[i], bn[i], a);
#pragma unroll 8
      for (int j = 0; j < 32; ++j) a = fmaf(wr[j], bn[128 + j], a);
    } else {
      int j0 = 32 + (q - 1)*160;
#pragma unroll 8
      for (int jj = 0; jj < 160; ++jj) {
        int j = j0 + jj;
        a = fmaf(wr[j], bn[128 + j], a);
      }
    }
  }
  a += __shfl_xor(a, 1); a += __shfl_xor(a, 2);
  if (q == 0) wbig[(size_t)k*32 + n] = a;
}

// ---------------- kmain (R8 verbatim): 256 rows x K-chunk; lane = 4 rows; wave = 16-k substripe
__global__ __launch_bounds__(256, 1) void kmain(
    const float* __restrict__ nf, const float* __restrict__ intf,
    const float* __restrict__ wbig, float* __restrict__ ndp, float* __restrict__ edp) {
  __shared__ float smem[36864];            // 144 KB: two 18432-float buffers
  const int tid = threadIdx.x;
  const int l = tid & 63;
  const int w = tid >> 6;
  const int bid = blockIdx.x;
  const bool isNode = bid < 128;

  int chunk, R0, kd0, nsteps;
  if (isNode) { chunk = bid & 3;  R0 = (bid >> 2)*256;         kd0 = chunk*512; nsteps = 8; }
  else        { int eb = bid-128; chunk = eb & 3; R0 = (eb >> 2)*256; kd0 = chunk*256; nsteps = 4; }

  const float* xsrc[16];
  {
    int sr = l >> 4, slot = l & 15;
#pragma unroll
    for (int i = 0; i < 16; ++i) {
      int r = w*64 + i*4 + sr;
      int grow = R0 + r;
      const float* rp;
      if (isNode) rp = nf + (size_t)grow*2048;
      else {
        int b = grow / 28, p = grow % 28;
        rp = intf + (size_t)(b*64 + d_pi[p]*8 + d_pj[p])*1024;
      }
      xsrc[i] = rp + kd0 + ((slot ^ (r & 7)) << 2);
    }
  }
  const float* wsrc = wbig + ((size_t)(isNode ? 0 : 2048) + kd0 + w*16)*32 + (l << 2);

  float acc[4][23];
#pragma unroll
  for (int j = 0; j < 4; ++j)
#pragma unroll
    for (int n = 0; n < 23; ++n) acc[j][n] = 0.f;

#define STAGE(T, D) do {                                                        \
    float* bd = smem + (D)*18432;                                               \
    _Pragma("unroll")                                                           \
    for (int i = 0; i < 16; ++i)                                                \
      load_lds16(xsrc[i] + (size_t)(T)*64, bd + (w*64 + i*4)*64);               \
    load_lds16(wsrc + (size_t)(T)*2048,       bd + 16384 + w*512);              \
    load_lds16(wsrc + (size_t)(T)*2048 + 256, bd + 16384 + w*512 + 256);        \
  } while (0)

  STAGE(0, 0);                              // prologue

  const int sl = l & 7;
#pragma unroll 1
  for (int t = 0; t < nsteps; ++t) {
    __builtin_amdgcn_s_barrier();
    if (t + 1 < nsteps) {
      STAGE(t + 1, (t + 1) & 1);
      asm volatile("s_waitcnt vmcnt(18)" ::: "memory");
    } else {
      asm volatile("s_waitcnt vmcnt(0)" ::: "memory");
    }

    const float4* bx = (const float4*)(smem + (t & 1)*18432);
    const float*  wl = smem + (t & 1)*18432 + 16384 + w*512;
#pragma unroll
    for (int k4 = 0; k4 < 4; ++k4) {
      float4 xr[4];
#pragma unroll
      for (int j = 0; j < 4; ++j)
        xr[j] = bx[(l + 64*j)*16 + ((w*4 + k4) ^ sl)];
#pragma unroll
      for (int e = 0; e < 4; ++e) {
        const float4* wv = (const float4*)(wl + (k4*4 + e)*32);
        float wreg[24];
#pragma unroll
        for (int v4 = 0; v4 < 6; ++v4) {
          float4 t4 = wv[v4];
          wreg[v4*4+0] = t4.x; wreg[v4*4+1] = t4.y; wreg[v4*4+2] = t4.z; wreg[v4*4+3] = t4.w;
        }
#pragma unroll
        for (int j = 0; j < 4; ++j) {
          float xs = (e == 0) ? xr[j].x : (e == 1) ? xr[j].y : (e == 2) ? xr[j].z : xr[j].w;
#pragma unroll
          for (int n = 0; n < 23; ++n)
            acc[j][n] = fmaf(xs, wreg[n], acc[j][n]);
        }
      }
    }
  }
#undef STAGE

  __syncthreads();
  float* red = smem;
#pragma unroll
  for (int j = 0; j < 4; ++j)
#pragma unroll
    for (int n = 0; n < 23; ++n)
      red[(w*256 + l + 64*j)*25 + n] = acc[j][n];
  __syncthreads();

  float* outp = isNode ? (ndp + ((size_t)chunk*8192  + R0)*23)
                       : (edp + ((size_t)chunk*28672 + R0)*23);
  for (int g = tid; g < 256*23; g += 256) {
    int r = g / 23, n = g - r*23;
    float s = red[r*25 + n] + red[(256 + r)*25 + n] + red[(512 + r)*25 + n] + red[(768 + r)*25 + n];
    outp[g] = s;
  }
}

// ---------------- kdiag_stage: R8 kmain's staging skeleton ONLY, x4 reps ----------------
// Identical grid/LDS/addressing/barrier/vmcnt structure; compute block removed.
// Time per rep == kmain's staging+sync skeleton cost. Runs LAST; writes to dead scratch.
__global__ __launch_bounds__(256, 1) void kdiag_stage(
    const float* __restrict__ nf, const float* __restrict__ intf,
    const float* __restrict__ wbig, float* __restrict__ dead) {
  __shared__ float smem[36864];
  const int tid = threadIdx.x;
  const int l = tid & 63;
  const int w = tid >> 6;
  const int bid = blockIdx.x;
  const bool isNode = bid < 128;

  int R0, kd0, nsteps;
  if (isNode) { R0 = (bid >> 2)*256; kd0 = (bid & 3)*512; nsteps = 8; }
  else        { int eb = bid-128; R0 = (eb >> 2)*256; kd0 = (eb & 3)*256; nsteps = 4; }

  const float* xsrc[16];
  {
    int sr = l >> 4, slot = l & 15;
#pragma unroll
    for (int i = 0; i < 16; ++i) {
      int r = w*64 + i*4 + sr;
      int grow = R0 + r;
      const float* rp;
      if (isNode) rp = nf + (size_t)grow*2048;
      else {
        int b = grow / 28, p = grow % 28;
        rp = intf + (size_t)(b*64 + d_pi[p]*8 + d_pj[p])*1024;
      }
      xsrc[i] = rp + kd0 + ((slot ^ (r & 7)) << 2);
    }
  }
  const float* wsrc = wbig + ((size_t)(isNode ? 0 : 2048) + kd0 + w*16)*32 + (l << 2);

#pragma unroll 1
  for (int rep = 0; rep < 4; ++rep) {
    {                                       // prologue stage -> buf 0
      float* bd = smem;
#pragma unroll
      for (int i = 0; i < 16; ++i)
        load_lds16(xsrc[i], bd + (w*64 + i*4)*64);
      load_lds16(wsrc,       bd + 16384 + w*512);
      load_lds16(wsrc + 256, bd + 16384 + w*512 + 256);
    }
#pragma unroll 1
    for (int t = 0; t < nsteps; ++t) {
      __builtin_amdgcn_s_barrier();
      if (t + 1 < nsteps) {
        float* bd = smem + ((t + 1) & 1)*18432;
#pragma unroll
        for (int i = 0; i < 16; ++i)
          load_lds16(xsrc[i] + (size_t)(t + 1)*64, bd + (w*64 + i*4)*64);
        load_lds16(wsrc + (size_t)(t + 1)*2048,       bd + 16384 + w*512);
        load_lds16(wsrc + (size_t)(t + 1)*2048 + 256, bd + 16384 + w*512 + 256);
        asm volatile("s_waitcnt vmcnt(18)" ::: "memory");
      } else {
        asm volatile("s_waitcnt vmcnt(0)" ::: "memory");
      }
      // compute removed (staging skeleton only)
    }
  }
  __syncthreads();
  if (tid == 0) dead[bid] = smem[0];        // deterministic (staged input data)
}

// ---------------- kcombine: one batch per block; sums 4 K-chunk partials ----------------
__global__ __launch_bounds__(256) void kcombine(
    const float* __restrict__ ndp, const float* __restrict__ edp,
    const float* __restrict__ bbig, const int* __restrict__ opairs,
    float* __restrict__ out) {
  __shared__ float snd[184];
  __shared__ int spos[8];
  int b = blockIdx.x, tid = threadIdx.x;
  if (tid < 184) {
    int o = tid / 23, n = tid % 23;
    float s = 0.f;
#pragma unroll
    for (int c = 0; c < 4; ++c)
      s += ndp[((size_t)c*8192 + b*8 + o)*23 + n];
    snd[tid] = s;
  } else if (tid < 192) {
    int r = tid - 184;
    int oi = opairs[b*16 + r*2], oj = opairs[b*16 + r*2 + 1];
    int a = min(oi, oj), bb = max(oi, oj);
    spos[r] = 7*a - (a*(a+1))/2 + bb - 1;
  }
  __syncthreads();
  for (int g = tid; g < 644; g += 256) {
    int p = g / 23, n = g % 23;
    float ed = 0.f;
#pragma unroll
    for (int c = 0; c < 4; ++c)
      ed += edp[((size_t)c*28672 + b*28 + p)*23 + n];
    float val = 0.5f*(snd[d_pi[p]*23 + n] + snd[d_pj[p]*23 + n]) + ed + bbig[n];
    int slot = -1, below = 0;
#pragma unroll
    for (int r = 0; r < 8; ++r) {
      int pl = spos[r];
      slot = (pl == p) ? r : slot;
      below += (pl < p) ? 1 : 0;
    }
    if (n == 0) {
      out[OUT_IND + b*28 + p] = 1.f/(1.f + expf(-val));
      out[OUT_LAB + b*28 + p] = (slot >= 0) ? 1.f : 0.f;
    } else {
      int h = n - 1;
      if (slot >= 0) {
        int rr = b*8 + slot;
        if (h < 5)      out[OUT_LRP + rr*5  + h]     = val;
        else if (h < 8) out[OUT_CRP + rr*3  + (h-5)] = val;
        else            out[OUT_MRP + rr*14 + (h-8)] = val;
      } else {
        int s = p - below;
        int rr = b*20 + s;
        if (h < 5)      out[OUT_LRN + rr*5  + h]     = val;
        else if (h < 8) out[OUT_CRN + rr*3  + (h-5)] = val;
        else            out[OUT_MRN + rr*14 + (h-8)] = val;
      }
    }
  }
}

extern "C" void kernel_launch(void* const* d_in, const int* in_sizes, int n_in,
                              void* d_out, int out_size, void* d_ws, size_t ws_size,
                              hipStream_t stream) {
  const float* nf     = (const float*)d_in[0];
  const float* intf   = (const float*)d_in[1];
  const int*   opairs = (const int*)d_in[2];
  const float* w_ind1 = (const float*)d_in[3];
  const float* b_ind1 = (const float*)d_in[4];
  const float* w_ind2 = (const float*)d_in[5];
  const float* b_ind2 = (const float*)d_in[6];
  const float* w_rel  = (const float*)d_in[7];
  const float* b_rel  = (const float*)d_in[8];
  const float* w_cr   = (const float*)d_in[9];
  const float* b_cr   = (const float*)d_in[10];
  const float* w_lr   = (const float*)d_in[11];
  const float* b_lr   = (const float*)d_in[12];
  const float* w_mr   = (const float*)d_in[13];
  const float* b_mr   = (const float*)d_in[14];
  float* out = (float*)d_out;
  float* ws  = (float*)d_ws;

  float* wbig = ws + WS_WBIG;
  float* bmat = ws + WS_BMAT;
  float* bbig = ws + WS_BBIG;
  float* ndp  = ws + WS_ND;
  float* edp  = ws + WS_ED;
  float* dead = ws + WS_DEAD;

  prep1<<<177, 256, 0, stream>>>(w_rel, w_ind2, w_lr, w_cr, w_mr,
                                 b_ind1, b_ind2, b_rel, b_lr, b_cr, b_mr, bmat, bbig);
  prep2<<<1152, 256, 0, stream>>>(w_ind1, w_rel, bmat, wbig);
  kmain<<<576, 256, 0, stream>>>(nf, intf, wbig, ndp, edp);
  kcombine<<<1024, 256, 0, stream>>>(ndp, edp, bbig, opairs, out);
  kdiag_stage<<<576, 256, 0, stream>>>(nf, intf, wbig, dead);   // diagnostic, runs last
}

// Round 12
// 108.664 us; speedup vs baseline: 2.1707x; 2.1707x over previous
//
#include <hip/hip_runtime.h>
#include <hip/hip_bf16.h>
#include <cstdint>
#include <cstddef>

// ws layout (float offsets)
#define WS_BMAT 0            // bmatT: 24*640 = 15360
#define WS_BBIG 15360        // 24 (+pad to 64)
#define WS_WBT  15424        // wbT bf16 [32][3072] = 98304 ushort = 49152 floats
#define WS_ND   64576        // 8*8192*23 = 1507328
#define WS_ED   1571904      // 4*28672*23 = 2637824  (end 4209728 floats)

// output offsets (floats)
#define OUT_IND 0
#define OUT_LAB 28672
#define OUT_LRP 57344
#define OUT_CRP 98304
#define OUT_MRP 122880
#define OUT_LRN 237568
#define OUT_CRN 339968
#define OUT_MRN 401408

typedef __attribute__((ext_vector_type(8))) short bf16x8;
typedef __attribute__((ext_vector_type(4))) float f32x4;

__device__ __constant__ int d_pi[28] = {0,0,0,0,0,0,0,1,1,1,1,1,1,2,2,2,2,2,3,3,3,3,4,4,4,5,5,6};
__device__ __constant__ int d_pj[28] = {1,2,3,4,5,6,7,2,3,4,5,6,7,3,4,5,6,7,4,5,6,7,5,6,7,6,7,7};

__device__ __forceinline__ float wh_at(const float* wlr, const float* wcr, const float* wmr,
                                       int j, int h) {
  return (h < 5) ? wlr[j*5 + h] : (h < 8) ? wcr[j*3 + (h-5)] : wmr[j*14 + (h-8)];
}

__device__ __forceinline__ short f2bf(float f) {
  __hip_bfloat16 h = __float2bfloat16(f);   // RNE; compiler packs pairs to cvt_pk
  short s;
  __builtin_memcpy(&s, &h, 2);
  return s;
}
__device__ __forceinline__ unsigned int f2bfu(float f) {
  __hip_bfloat16 h = __float2bfloat16(f);
  unsigned short s;
  __builtin_memcpy(&s, &h, 2);
  return (unsigned int)s;
}

// ---------------- prep1: bmatT[24][640] and b_big (dword stores only) ----------------
__global__ __launch_bounds__(256) void prep1(
    const float* __restrict__ w_rel, const float* __restrict__ w_ind2,
    const float* __restrict__ w_lr, const float* __restrict__ w_cr, const float* __restrict__ w_mr,
    const float* __restrict__ b_ind1, const float* __restrict__ b_ind2,
    const float* __restrict__ b_rel,
    const float* __restrict__ b_lr, const float* __restrict__ b_cr, const float* __restrict__ b_mr,
    float* __restrict__ bmat, float* __restrict__ bbig) {
  int bid = blockIdx.x, tid = threadIdx.x;
  if (bid < 128) {                         // T1 col m: bmatT[1+h][m] = sum_j Wrel2[m][j]*Wh[j][h]
    int m = bid;
    __shared__ float swr[512];
    const float* wr2 = w_rel + (size_t)(3072 + m)*512;
    swr[tid]       = wr2[tid];
    swr[tid + 256] = wr2[tid + 256];
    __syncthreads();
    int h = tid >> 3, q = tid & 7;
    if (h < 22) {
      float a = 0.f;
#pragma unroll 8
      for (int jj = 0; jj < 64; ++jj) {
        int j = jj*8 + q;
        a = fmaf(swr[j], wh_at(w_lr, w_cr, w_mr, j, h), a);
      }
      a += __shfl_xor(a, 1); a += __shfl_xor(a, 2); a += __shfl_xor(a, 4);
      if (q == 0) bmat[(1 + h)*640 + m] = a;
    }
    if (tid == 248) bmat[0*640 + m]  = w_ind2[m];
    if (tid == 249) bmat[23*640 + m] = 0.f;
  } else if (bid == 128) {                 // biases
    __shared__ float sbrel[512];
    for (int j = tid; j < 512; j += 256) {
      float a = b_rel[j];
#pragma unroll 4
      for (int m = 0; m < 128; ++m)
        a = fmaf(b_ind1[m], w_rel[(size_t)(3072 + m)*512 + j], a);
      sbrel[j] = a;
    }
    __syncthreads();
    int h = tid >> 3, q = tid & 7;
    if (h < 22) {
      float bh = (h < 5) ? b_lr[h] : (h < 8) ? b_cr[h-5] : b_mr[h-8];
      float a = 0.f;
#pragma unroll 8
      for (int jj = 0; jj < 64; ++jj) {
        int j = jj*8 + q;
        a = fmaf(sbrel[j], wh_at(w_lr, w_cr, w_mr, j, h), a);
      }
      a += __shfl_xor(a, 1); a += __shfl_xor(a, 2); a += __shfl_xor(a, 4);
      if (q == 0) bbig[1 + h] = a + bh;
    } else if (tid >= 248) {
      int q2 = tid & 7;
      float a = 0.f;
#pragma unroll
      for (int t = 0; t < 16; ++t)
        a = fmaf(b_ind1[q2*16 + t], w_ind2[q2*16 + t], a);
      a += __shfl_xor(a, 1); a += __shfl_xor(a, 2); a += __shfl_xor(a, 4);
      if (tid == 248) bbig[0]  = a + b_ind2[0];
      if (tid == 250) bbig[23] = 0.f;
    }
  } else {                                 // WhE: bmatT[n][128+j], bids 129..176
    int idx = (bid - 129)*256 + tid;
    int j = idx / 24, n = idx % 24;
    float v = (n >= 1 && n <= 22) ? wh_at(w_lr, w_cr, w_mr, j, n - 1) : 0.f;
    bmat[n*640 + 128 + j] = v;
  }
}

// ---------------- prep2: wbT bf16 [32][3072], PACKED-PAIR DWORD stores ----------------
// quartet gid -> (k2, n, kp): k = 2*k2 + kp. Pair partner is tid^4 (same wave);
// one lane stores both halves as a single aligned uint32 -> no sub-dword global writes.
__global__ __launch_bounds__(256) void prep2(
    const float* __restrict__ w_ind1, const float* __restrict__ w_rel,
    const float* __restrict__ bmat, unsigned int* __restrict__ wbT32) {
  int g = blockIdx.x*256 + threadIdx.x;    // 393216 = 98304 outputs x 4 quarters
  int gid = g >> 2, q = g & 3;
  int kp = gid & 1, n = (gid >> 1) & 31, k2 = gid >> 6;
  int k = k2*2 + kp;
  float a = 0.f;
  if (n < 23) {
    const float* wr = w_rel + (size_t)k*512;
    const float* bn = bmat + n*640;
    if (q == 0) {
      const float* w1 = w_ind1 + (size_t)k*128;
#pragma unroll 8
      for (int i = 0; i < 128; ++i) a = fmaf(w1[i], bn[i], a);
#pragma unroll 8
      for (int j = 0; j < 32; ++j) a = fmaf(wr[j], bn[128 + j], a);
    } else {
      int j0 = 32 + (q - 1)*160;
#pragma unroll 8
      for (int jj = 0; jj < 160; ++jj) {
        int j = j0 + jj;
        a = fmaf(wr[j], bn[128 + j], a);
      }
    }
  }
  a += __shfl_xor(a, 1); a += __shfl_xor(a, 2);   // reduce quarters -> q==0 holds value
  float other = __shfl_xor(a, 4);                 // partner k (kp flipped)
  if (q == 0 && kp == 0) {
    unsigned int lo = f2bfu(a), hi = f2bfu(other);
    wbT32[(size_t)n*1536 + k2] = lo | (hi << 16);
  }
}

// ---------------- kmain_mfma: one independent wave-job = 64 rows x 256 k ----------------
// ZERO LDS, ZERO barriers, ZERO inline asm. A: X fp32 from global, cvt->bf16.
// B: wbT bf16 (L2-resident). 8 x mfma_f32_16x16x32_bf16 per K32-step.
// A/B use the identical slot->k map (k-permutation cancels); C/D: col=l&15, row=(l>>4)*4+reg.
// Epilogue: direct per-element global stores of the fragments (dword-granular).
__global__ __launch_bounds__(256) void kmain_mfma(
    const float* __restrict__ nf, const float* __restrict__ intf,
    const unsigned short* __restrict__ wbT, float* __restrict__ ndp, float* __restrict__ edp) {
  const int tid = threadIdx.x;
  const int l = tid & 63;
  const int w = tid >> 6;
  const int wid = blockIdx.x*4 + w;        // 2816 wave-jobs
  const bool isNode = wid < 1024;

  int rg, chunk, kbase;
  if (isNode) { rg = wid >> 3; chunk = wid & 7; kbase = 0; }
  else        { int e = wid - 1024; rg = e >> 2; chunk = e & 3; kbase = 2048; }
  const int R0 = rg*64;
  const int kd0 = chunk*256;

  const int ln = l & 15, lg = l >> 4;

  // A sources: m-tile i -> row R0 + i*16 + ln, fp32, k offset kd0 + lg*8
  const float* xp[4];
#pragma unroll
  for (int i = 0; i < 4; ++i) {
    int grow = R0 + i*16 + ln;
    const float* rp;
    if (isNode) rp = nf + (size_t)grow*2048;
    else {
      int b = grow / 28, p = grow - b*28;
      rp = intf + (size_t)(b*64 + d_pi[p]*8 + d_pj[p])*1024;
    }
    xp[i] = rp + kd0 + lg*8;
  }
  // B sources: n-tile 0 rows ln, n-tile 1 rows 16+ln
  const unsigned short* wp0 = wbT + (size_t)ln*3072 + kbase + kd0 + lg*8;
  const unsigned short* wp1 = wp0 + (size_t)16*3072;

  f32x4 acc[4][2];
#pragma unroll
  for (int i = 0; i < 4; ++i) {
    acc[i][0] = (f32x4){0.f, 0.f, 0.f, 0.f};
    acc[i][1] = (f32x4){0.f, 0.f, 0.f, 0.f};
  }

#pragma unroll 2
  for (int t = 0; t < 8; ++t) {
    const int ko = t*32;
    bf16x8 b0 = *(const bf16x8*)(wp0 + ko);
    bf16x8 b1 = *(const bf16x8*)(wp1 + ko);
#pragma unroll
    for (int i = 0; i < 4; ++i) {
      float4 xa = *(const float4*)(xp[i] + ko);
      float4 xb = *(const float4*)(xp[i] + ko + 4);
      bf16x8 a;
      a[0] = f2bf(xa.x); a[1] = f2bf(xa.y); a[2] = f2bf(xa.z); a[3] = f2bf(xa.w);
      a[4] = f2bf(xb.x); a[5] = f2bf(xb.y); a[6] = f2bf(xb.z); a[7] = f2bf(xb.w);
      acc[i][0] = __builtin_amdgcn_mfma_f32_16x16x32_bf16(a, b0, acc[i][0], 0, 0, 0);
      acc[i][1] = __builtin_amdgcn_mfma_f32_16x16x32_bf16(a, b1, acc[i][1], 0, 0, 0);
    }
  }

  // epilogue: direct fragment stores (wave jointly covers each 23-float row)
  float* outp = isNode ? (ndp + ((size_t)chunk*8192  + R0)*23)
                       : (edp + ((size_t)chunk*28672 + R0)*23);
#pragma unroll
  for (int i = 0; i < 4; ++i) {
#pragma unroll
    for (int tn = 0; tn < 2; ++tn) {
      int n = tn*16 + ln;
      if (n < 23) {
#pragma unroll
        for (int r = 0; r < 4; ++r)
          outp[(size_t)(i*16 + lg*4 + r)*23 + n] = acc[i][tn][r];
      }
    }
  }
}

// ---------------- kcombine: one batch per block; sums 8 node / 4 edge partials ----------------
__global__ __launch_bounds__(256) void kcombine(
    const float* __restrict__ ndp, const float* __restrict__ edp,
    const float* __restrict__ bbig, const int* __restrict__ opairs,
    float* __restrict__ out) {
  __shared__ float snd[184];
  __shared__ int spos[8];
  int b = blockIdx.x, tid = threadIdx.x;
  if (tid < 184) {
    int o = tid / 23, n = tid % 23;
    float s = 0.f;
#pragma unroll
    for (int c = 0; c < 8; ++c)
      s += ndp[((size_t)c*8192 + b*8 + o)*23 + n];
    snd[tid] = s;
  } else if (tid < 192) {
    int r = tid - 184;
    int oi = opairs[b*16 + r*2], oj = opairs[b*16 + r*2 + 1];
    int a = min(oi, oj), bb = max(oi, oj);
    spos[r] = 7*a - (a*(a+1))/2 + bb - 1;
  }
  __syncthreads();
  for (int g = tid; g < 644; g += 256) {
    int p = g / 23, n = g % 23;
    float ed = 0.f;
#pragma unroll
    for (int c = 0; c < 4; ++c)
      ed += edp[((size_t)c*28672 + b*28 + p)*23 + n];
    float val = 0.5f*(snd[d_pi[p]*23 + n] + snd[d_pj[p]*23 + n]) + ed + bbig[n];
    int slot = -1, below = 0;
#pragma unroll
    for (int r = 0; r < 8; ++r) {
      int pl = spos[r];
      slot = (pl == p) ? r : slot;
      below += (pl < p) ? 1 : 0;
    }
    if (n == 0) {
      out[OUT_IND + b*28 + p] = 1.f/(1.f + expf(-val));
      out[OUT_LAB + b*28 + p] = (slot >= 0) ? 1.f : 0.f;
    } else {
      int h = n - 1;
      if (slot >= 0) {
        int rr = b*8 + slot;
        if (h < 5)      out[OUT_LRP + rr*5  + h]     = val;
        else if (h < 8) out[OUT_CRP + rr*3  + (h-5)] = val;
        else            out[OUT_MRP + rr*14 + (h-8)] = val;
      } else {
        int s = p - below;
        int rr = b*20 + s;
        if (h < 5)      out[OUT_LRN + rr*5  + h]     = val;
        else if (h < 8) out[OUT_CRN + rr*3  + (h-5)] = val;
        else            out[OUT_MRN + rr*14 + (h-8)] = val;
      }
    }
  }
}

extern "C" void kernel_launch(void* const* d_in, const int* in_sizes, int n_in,
                              void* d_out, int out_size, void* d_ws, size_t ws_size,
                              hipStream_t stream) {
  const float* nf     = (const float*)d_in[0];
  const float* intf   = (const float*)d_in[1];
  const int*   opairs = (const int*)d_in[2];
  const float* w_ind1 = (const float*)d_in[3];
  const float* b_ind1 = (const float*)d_in[4];
  const float* w_ind2 = (const float*)d_in[5];
  const float* b_ind2 = (const float*)d_in[6];
  const float* w_rel  = (const float*)d_in[7];
  const float* b_rel  = (const float*)d_in[8];
  const float* w_cr   = (const float*)d_in[9];
  const float* b_cr   = (const float*)d_in[10];
  const float* w_lr   = (const float*)d_in[11];
  const float* b_lr   = (const float*)d_in[12];
  const float* w_mr   = (const float*)d_in[13];
  const float* b_mr   = (const float*)d_in[14];
  float* out = (float*)d_out;
  float* ws  = (float*)d_ws;

  float*          bmat  = ws + WS_BMAT;
  float*          bbig  = ws + WS_BBIG;
  unsigned int*   wbT32 = (unsigned int*)(ws + WS_WBT);
  unsigned short* wbT   = (unsigned short*)(ws + WS_WBT);
  float*          ndp   = ws + WS_ND;
  float*          edp   = ws + WS_ED;

  prep1<<<177, 256, 0, stream>>>(w_rel, w_ind2, w_lr, w_cr, w_mr,
                                 b_ind1, b_ind2, b_rel, b_lr, b_cr, b_mr, bmat, bbig);
  prep2<<<1536, 256, 0, stream>>>(w_ind1, w_rel, bmat, wbT32);
  kmain_mfma<<<704, 256, 0, stream>>>(nf, intf, wbT, ndp, edp);
  kcombine<<<1024, 256, 0, stream>>>(ndp, edp, bbig, opairs, out);
}

// Round 13
// 108.311 us; speedup vs baseline: 2.1777x; 1.0033x over previous
//
#include <hip/hip_runtime.h>
#include <hip/hip_bf16.h>
#include <cstdint>
#include <cstddef>

// ws layout (float offsets)
#define WS_BMAT 0            // bmatT: 24*640 = 15360
#define WS_BBIG 15360        // 24 (+pad to 64)
#define WS_WBT  15424        // wbT bf16 [32][3072] = 98304 ushort = 49152 floats
#define WS_ND   64576        // 8*8192*23 = 1507328
#define WS_ED   1571904      // 4*28672*23 = 2637824  (end 4209728 floats)

// output offsets (floats)
#define OUT_IND 0
#define OUT_LAB 28672
#define OUT_LRP 57344
#define OUT_CRP 98304
#define OUT_MRP 122880
#define OUT_LRN 237568
#define OUT_CRN 339968
#define OUT_MRN 401408

typedef __attribute__((ext_vector_type(8))) short bf16x8;
typedef __attribute__((ext_vector_type(4))) float f32x4;

__device__ __constant__ int d_pi[28] = {0,0,0,0,0,0,0,1,1,1,1,1,1,2,2,2,2,2,3,3,3,3,4,4,4,5,5,6};
__device__ __constant__ int d_pj[28] = {1,2,3,4,5,6,7,2,3,4,5,6,7,3,4,5,6,7,4,5,6,7,5,6,7,6,7,7};

__device__ __forceinline__ float wh_at(const float* wlr, const float* wcr, const float* wmr,
                                       int j, int h) {
  return (h < 5) ? wlr[j*5 + h] : (h < 8) ? wcr[j*3 + (h-5)] : wmr[j*14 + (h-8)];
}

__device__ __forceinline__ short f2bf(float f) {
  __hip_bfloat16 h = __float2bfloat16(f);   // RNE; compiler packs pairs to cvt_pk
  short s;
  __builtin_memcpy(&s, &h, 2);
  return s;
}
__device__ __forceinline__ unsigned int f2bfu(float f) {
  __hip_bfloat16 h = __float2bfloat16(f);
  unsigned short s;
  __builtin_memcpy(&s, &h, 2);
  return (unsigned int)s;
}

// ---------------- prep1: bmatT[24][640] and b_big (dword stores only) ----------------
__global__ __launch_bounds__(256) void prep1(
    const float* __restrict__ w_rel, const float* __restrict__ w_ind2,
    const float* __restrict__ w_lr, const float* __restrict__ w_cr, const float* __restrict__ w_mr,
    const float* __restrict__ b_ind1, const float* __restrict__ b_ind2,
    const float* __restrict__ b_rel,
    const float* __restrict__ b_lr, const float* __restrict__ b_cr, const float* __restrict__ b_mr,
    float* __restrict__ bmat, float* __restrict__ bbig) {
  int bid = blockIdx.x, tid = threadIdx.x;
  if (bid < 128) {                         // T1 col m: bmatT[1+h][m] = sum_j Wrel2[m][j]*Wh[j][h]
    int m = bid;
    __shared__ float swr[512];
    const float* wr2 = w_rel + (size_t)(3072 + m)*512;
    swr[tid]       = wr2[tid];
    swr[tid + 256] = wr2[tid + 256];
    __syncthreads();
    int h = tid >> 3, q = tid & 7;
    if (h < 22) {
      float a = 0.f;
#pragma unroll 8
      for (int jj = 0; jj < 64; ++jj) {
        int j = jj*8 + q;
        a = fmaf(swr[j], wh_at(w_lr, w_cr, w_mr, j, h), a);
      }
      a += __shfl_xor(a, 1); a += __shfl_xor(a, 2); a += __shfl_xor(a, 4);
      if (q == 0) bmat[(1 + h)*640 + m] = a;
    }
    if (tid == 248) bmat[0*640 + m]  = w_ind2[m];
    if (tid == 249) bmat[23*640 + m] = 0.f;
  } else if (bid == 128) {                 // biases
    __shared__ float sbrel[512];
    for (int j = tid; j < 512; j += 256) {
      float a = b_rel[j];
#pragma unroll 4
      for (int m = 0; m < 128; ++m)
        a = fmaf(b_ind1[m], w_rel[(size_t)(3072 + m)*512 + j], a);
      sbrel[j] = a;
    }
    __syncthreads();
    int h = tid >> 3, q = tid & 7;
    if (h < 22) {
      float bh = (h < 5) ? b_lr[h] : (h < 8) ? b_cr[h-5] : b_mr[h-8];
      float a = 0.f;
#pragma unroll 8
      for (int jj = 0; jj < 64; ++jj) {
        int j = jj*8 + q;
        a = fmaf(sbrel[j], wh_at(w_lr, w_cr, w_mr, j, h), a);
      }
      a += __shfl_xor(a, 1); a += __shfl_xor(a, 2); a += __shfl_xor(a, 4);
      if (q == 0) bbig[1 + h] = a + bh;
    } else if (tid >= 248) {
      int q2 = tid & 7;
      float a = 0.f;
#pragma unroll
      for (int t = 0; t < 16; ++t)
        a = fmaf(b_ind1[q2*16 + t], w_ind2[q2*16 + t], a);
      a += __shfl_xor(a, 1); a += __shfl_xor(a, 2); a += __shfl_xor(a, 4);
      if (tid == 248) bbig[0]  = a + b_ind2[0];
      if (tid == 250) bbig[23] = 0.f;
    }
  } else {                                 // WhE: bmatT[n][128+j], bids 129..176
    int idx = (bid - 129)*256 + tid;
    int j = idx / 24, n = idx % 24;
    float v = (n >= 1 && n <= 22) ? wh_at(w_lr, w_cr, w_mr, j, n - 1) : 0.f;
    bmat[n*640 + 128 + j] = v;
  }
}

// ---------------- prep2: wbT bf16 [32][3072], PACKED-PAIR DWORD stores ----------------
__global__ __launch_bounds__(256) void prep2(
    const float* __restrict__ w_ind1, const float* __restrict__ w_rel,
    const float* __restrict__ bmat, unsigned int* __restrict__ wbT32) {
  int g = blockIdx.x*256 + threadIdx.x;    // 393216 = 98304 outputs x 4 quarters
  int gid = g >> 2, q = g & 3;
  int kp = gid & 1, n = (gid >> 1) & 31, k2 = gid >> 6;
  int k = k2*2 + kp;
  float a = 0.f;
  if (n < 23) {
    const float* wr = w_rel + (size_t)k*512;
    const float* bn = bmat + n*640;
    if (q == 0) {
      const float* w1 = w_ind1 + (size_t)k*128;
#pragma unroll 8
      for (int i = 0; i < 128; ++i) a = fmaf(w1[i], bn[i], a);
#pragma unroll 8
      for (int j = 0; j < 32; ++j) a = fmaf(wr[j], bn[128 + j], a);
    } else {
      int j0 = 32 + (q - 1)*160;
#pragma unroll 8
      for (int jj = 0; jj < 160; ++jj) {
        int j = j0 + jj;
        a = fmaf(wr[j], bn[128 + j], a);
      }
    }
  }
  a += __shfl_xor(a, 1); a += __shfl_xor(a, 2);   // reduce quarters -> q==0 holds value
  float other = __shfl_xor(a, 4);                 // partner k (kp flipped)
  if (q == 0 && kp == 0) {
    unsigned int lo = f2bfu(a), hi = f2bfu(other);
    wbT32[(size_t)n*1536 + k2] = lo | (hi << 16);
  }
}

// ---------------- kmain_mfma: one independent wave-job = 64 rows x 256 k ----------------
// A: X fp32 from global, cvt->bf16. B: wbT bf16 (L2-resident).
// 8 x mfma_f32_16x16x32_bf16 per K32-step; A/B share the slot->k map (k-perm cancels);
// C/D: col=l&15, row=(l>>4)*4+reg. Epilogue: wave-private LDS transpose (+__syncthreads)
// then fully-coalesced dword row stores (dense lines -> cold-write friendly).
__global__ __launch_bounds__(256) void kmain_mfma(
    const float* __restrict__ nf, const float* __restrict__ intf,
    const unsigned short* __restrict__ wbT, float* __restrict__ ndp, float* __restrict__ edp) {
  __shared__ float red[4][1600];           // wave-private transpose buffers (25.6 KB)
  const int tid = threadIdx.x;
  const int l = tid & 63;
  const int w = tid >> 6;
  const int wid = blockIdx.x*4 + w;        // 2816 wave-jobs
  const bool isNode = wid < 1024;

  int rg, chunk, kbase;
  if (isNode) { rg = wid >> 3; chunk = wid & 7; kbase = 0; }
  else        { int e = wid - 1024; rg = e >> 2; chunk = e & 3; kbase = 2048; }
  const int R0 = rg*64;
  const int kd0 = chunk*256;

  const int ln = l & 15, lg = l >> 4;

  // A sources: m-tile i -> row R0 + i*16 + ln, fp32, k offset kd0 + lg*8
  const float* xp[4];
#pragma unroll
  for (int i = 0; i < 4; ++i) {
    int grow = R0 + i*16 + ln;
    const float* rp;
    if (isNode) rp = nf + (size_t)grow*2048;
    else {
      int b = grow / 28, p = grow - b*28;
      rp = intf + (size_t)(b*64 + d_pi[p]*8 + d_pj[p])*1024;
    }
    xp[i] = rp + kd0 + lg*8;
  }
  // B sources: n-tile 0 rows ln, n-tile 1 rows 16+ln
  const unsigned short* wp0 = wbT + (size_t)ln*3072 + kbase + kd0 + lg*8;
  const unsigned short* wp1 = wp0 + (size_t)16*3072;

  f32x4 acc[4][2];
#pragma unroll
  for (int i = 0; i < 4; ++i) {
    acc[i][0] = (f32x4){0.f, 0.f, 0.f, 0.f};
    acc[i][1] = (f32x4){0.f, 0.f, 0.f, 0.f};
  }

#pragma unroll 2
  for (int t = 0; t < 8; ++t) {
    const int ko = t*32;
    bf16x8 b0 = *(const bf16x8*)(wp0 + ko);
    bf16x8 b1 = *(const bf16x8*)(wp1 + ko);
#pragma unroll
    for (int i = 0; i < 4; ++i) {
      float4 xa = *(const float4*)(xp[i] + ko);
      float4 xb = *(const float4*)(xp[i] + ko + 4);
      bf16x8 a;
      a[0] = f2bf(xa.x); a[1] = f2bf(xa.y); a[2] = f2bf(xa.z); a[3] = f2bf(xa.w);
      a[4] = f2bf(xb.x); a[5] = f2bf(xb.y); a[6] = f2bf(xb.z); a[7] = f2bf(xb.w);
      acc[i][0] = __builtin_amdgcn_mfma_f32_16x16x32_bf16(a, b0, acc[i][0], 0, 0, 0);
      acc[i][1] = __builtin_amdgcn_mfma_f32_16x16x32_bf16(a, b1, acc[i][1], 0, 0, 0);
    }
  }

  // epilogue: frag -> wave-private LDS (pitch 25) -> barrier -> coalesced row stores
  float* rw = red[w];
#pragma unroll
  for (int i = 0; i < 4; ++i)
#pragma unroll
    for (int tn = 0; tn < 2; ++tn) {
      int n = tn*16 + ln;
      if (n < 23) {
#pragma unroll
        for (int r = 0; r < 4; ++r)
          rw[(i*16 + lg*4 + r)*25 + n] = acc[i][tn][r];
      }
    }
  __syncthreads();                         // safe ordering (no inline-asm wait; rule #18)
  float* outp = isNode ? (ndp + ((size_t)chunk*8192  + R0)*23)
                       : (edp + ((size_t)chunk*28672 + R0)*23);
#pragma unroll
  for (int i = 0; i < 23; ++i) {
    int g = i*64 + l;
    int r = g / 23, n = g - r*23;
    outp[g] = rw[r*25 + n];
  }
}

// ---------------- kcombine: one batch per block; sums 8 node / 4 edge partials ----------------
__global__ __launch_bounds__(256) void kcombine(
    const float* __restrict__ ndp, const float* __restrict__ edp,
    const float* __restrict__ bbig, const int* __restrict__ opairs,
    float* __restrict__ out) {
  __shared__ float snd[184];
  __shared__ int spos[8];
  int b = blockIdx.x, tid = threadIdx.x;
  if (tid < 184) {
    int o = tid / 23, n = tid % 23;
    float s = 0.f;
#pragma unroll
    for (int c = 0; c < 8; ++c)
      s += ndp[((size_t)c*8192 + b*8 + o)*23 + n];
    snd[tid] = s;
  } else if (tid < 192) {
    int r = tid - 184;
    int oi = opairs[b*16 + r*2], oj = opairs[b*16 + r*2 + 1];
    int a = min(oi, oj), bb = max(oi, oj);
    spos[r] = 7*a - (a*(a+1))/2 + bb - 1;
  }
  __syncthreads();
  for (int g = tid; g < 644; g += 256) {
    int p = g / 23, n = g % 23;
    float ed = 0.f;
#pragma unroll
    for (int c = 0; c < 4; ++c)
      ed += edp[((size_t)c*28672 + b*28 + p)*23 + n];
    float val = 0.5f*(snd[d_pi[p]*23 + n] + snd[d_pj[p]*23 + n]) + ed + bbig[n];
    int slot = -1, below = 0;
#pragma unroll
    for (int r = 0; r < 8; ++r) {
      int pl = spos[r];
      slot = (pl == p) ? r : slot;
      below += (pl < p) ? 1 : 0;
    }
    if (n == 0) {
      out[OUT_IND + b*28 + p] = 1.f/(1.f + expf(-val));
      out[OUT_LAB + b*28 + p] = (slot >= 0) ? 1.f : 0.f;
    } else {
      int h = n - 1;
      if (slot >= 0) {
        int rr = b*8 + slot;
        if (h < 5)      out[OUT_LRP + rr*5  + h]     = val;
        else if (h < 8) out[OUT_CRP + rr*3  + (h-5)] = val;
        else            out[OUT_MRP + rr*14 + (h-8)] = val;
      } else {
        int s = p - below;
        int rr = b*20 + s;
        if (h < 5)      out[OUT_LRN + rr*5  + h]     = val;
        else if (h < 8) out[OUT_CRN + rr*3  + (h-5)] = val;
        else            out[OUT_MRN + rr*14 + (h-8)] = val;
      }
    }
  }
}

extern "C" void kernel_launch(void* const* d_in, const int* in_sizes, int n_in,
                              void* d_out, int out_size, void* d_ws, size_t ws_size,
                              hipStream_t stream) {
  const float* nf     = (const float*)d_in[0];
  const float* intf   = (const float*)d_in[1];
  const int*   opairs = (const int*)d_in[2];
  const float* w_ind1 = (const float*)d_in[3];
  const float* b_ind1 = (const float*)d_in[4];
  const float* w_ind2 = (const float*)d_in[5];
  const float* b_ind2 = (const float*)d_in[6];
  const float* w_rel  = (const float*)d_in[7];
  const float* b_rel  = (const float*)d_in[8];
  const float* w_cr   = (const float*)d_in[9];
  const float* b_cr   = (const float*)d_in[10];
  const float* w_lr   = (const float*)d_in[11];
  const float* b_lr   = (const float*)d_in[12];
  const float* w_mr   = (const float*)d_in[13];
  const float* b_mr   = (const float*)d_in[14];
  float* out = (float*)d_out;
  float* ws  = (float*)d_ws;

  float*          bmat  = ws + WS_BMAT;
  float*          bbig  = ws + WS_BBIG;
  unsigned int*   wbT32 = (unsigned int*)(ws + WS_WBT);
  unsigned short* wbT   = (unsigned short*)(ws + WS_WBT);
  float*          ndp   = ws + WS_ND;
  float*          edp   = ws + WS_ED;

  prep1<<<177, 256, 0, stream>>>(w_rel, w_ind2, w_lr, w_cr, w_mr,
                                 b_ind1, b_ind2, b_rel, b_lr, b_cr, b_mr, bmat, bbig);
  prep2<<<1536, 256, 0, stream>>>(w_ind1, w_rel, bmat, wbT32);
  kmain_mfma<<<704, 256, 0, stream>>>(nf, intf, wbT, ndp, edp);
  kcombine<<<1024, 256, 0, stream>>>(ndp, edp, bbig, opairs, out);
}